// Round 3
// baseline (417.977 us; speedup 1.0000x reference)
//
#include <hip/hip_runtime.h>
#include <hip/hip_bf16.h>

// B=32, T=2048, D=512
// out[b,d] = softmax_d( sum_t Va[t]*tanh((x0@Wa)[b,d] + (x1@Wh)[b,t,d]) ) * sum_{t,i} x1[b,t,i]

typedef __attribute__((ext_vector_type(8))) short bf16x8;
typedef __attribute__((ext_vector_type(4))) float f32x4;

__device__ __forceinline__ ushort f2bf(float f) {
  __hip_bfloat16 h = __float2bfloat16(f);          // RNE, -> v_cvt
  union { __hip_bfloat16 h; ushort u; } c; c.h = h;
  return c.u;
}

__device__ __forceinline__ ushort2 cvt2(float x, float y) {
  float2 f; f.x = x; f.y = y;
  __hip_bfloat162 h = __float22bfloat162_rn(f);    // -> v_cvt_pk_bf16_f32
  union { __hip_bfloat162 h; ushort2 u; } c; c.h = h;
  return c.u;
}

// W_h (K=512 x N=512 row-major f32) -> WhT bf16 (N x K), coalesced tiled transpose
__global__ __launch_bounds__(256) void prep_wht(const float* __restrict__ Wh,
                                                ushort* __restrict__ WhT) {
  __shared__ float tile[64][65];
  const int bx = blockIdx.x & 7;    // n-tile
  const int by = blockIdx.x >> 3;   // k-tile
  const int c  = threadIdx.x & 63;
  const int r0 = threadIdx.x >> 6;  // 0..3
#pragma unroll
  for (int i = 0; i < 16; ++i) {
    int r = r0 * 16 + i;
    tile[r][c] = Wh[(size_t)(by * 64 + r) * 512 + bx * 64 + c];
  }
  __syncthreads();
#pragma unroll
  for (int i = 0; i < 16; ++i) {
    int r = r0 * 16 + i;
    WhT[(size_t)(bx * 64 + r) * 512 + by * 64 + c] = f2bf(tile[c][r]);
  }
}

// s1[b,d] = sum_k x0[b,k] * Wa[k,d]   (fp32), 64 blocks x 256 threads
__global__ __launch_bounds__(256) void prep_s1(const float* __restrict__ x0,
                                               const float* __restrict__ Wa,
                                               float* __restrict__ s1) {
  const int b = blockIdx.x >> 1;
  const int d = (blockIdx.x & 1) * 256 + threadIdx.x;
  const float* x0b = x0 + b * 512;
  float acc = 0.f;
#pragma unroll 8
  for (int k = 0; k < 512; ++k) acc = fmaf(x0b[k], Wa[(size_t)k * 512 + d], acc);
  s1[b * 512 + d] = acc;
}

// Main fused kernel: 128x128 tile of s2 = x1[b] @ Wh, epilogue tanh(s2+s1)*Va[t],
// reduce over t, atomicAdd into o[b,:]. sum(x1[b]) accumulated by nt==0 blocks.
__global__ __launch_bounds__(256, 3) void main_gemm(
    const float* __restrict__ x1, const ushort* __restrict__ WhT,
    const float* __restrict__ s1, const float* __restrict__ Va,
    float* __restrict__ o, float* __restrict__ S) {
  __shared__ ushort As[128][72];   // 144B row stride -> 2-way bank alias (free)
  __shared__ ushort Bs[128][72];
  __shared__ float sred[4];

  // XCD-chunked swizzle: each XCD gets a contiguous chunk of 256 logical blocks;
  // the 4 nt-sharers of one A-panel are adjacent slots on the SAME XCD.
  const int phys = blockIdx.x;                    // 2048 blocks
  const int lid  = (phys & 7) * 256 + (phys >> 3);
  const int b    = lid >> 6;
  const int mt   = (lid >> 2) & 15;
  const int nt   = lid & 3;

  const int tid  = threadIdx.x;
  const int wid  = tid >> 6, lane = tid & 63;
  const int wr   = wid >> 1, wc = wid & 1;        // 2x2 wave grid, 64x64 each
  const int lr   = lane & 15, lg = lane >> 4;

  f32x4 acc[4][4];
  const f32x4 zero = {0.f, 0.f, 0.f, 0.f};
#pragma unroll
  for (int mf = 0; mf < 4; ++mf)
#pragma unroll
    for (int nf = 0; nf < 4; ++nf) acc[mf][nf] = zero;

  const float*  x1b = x1 + (size_t)(b * 2048 + mt * 128) * 512;
  const ushort* wb  = WhT + (size_t)(nt * 128) * 512;

  float4 areg[8];
  uint4  breg[4];

  // prologue: issue tile-0 loads
#pragma unroll
  for (int i = 0; i < 8; ++i) {
    int s = tid + i * 256;
    areg[i] = *(const float4*)(x1b + (size_t)(s >> 4) * 512 + (s & 15) * 4);
  }
#pragma unroll
  for (int i = 0; i < 4; ++i) {
    int s = tid + i * 256;
    breg[i] = *(const uint4*)(wb + (size_t)(s >> 3) * 512 + (s & 7) * 8);
  }

  float ssum = 0.f;
  for (int ks = 0; ks < 8; ++ks) {
    __syncthreads();                // previous tile fully consumed
    // ---- write staged regs -> LDS (cvt_pk f32->bf16) ----
#pragma unroll
    for (int i = 0; i < 8; ++i) {
      int s = tid + i * 256;
      float4 a = areg[i];
      if (nt == 0) ssum += (a.x + a.y) + (a.z + a.w);
      ushort2 lo = cvt2(a.x, a.y), hi = cvt2(a.z, a.w);
      ushort4 u; u.x = lo.x; u.y = lo.y; u.z = hi.x; u.w = hi.y;
      *(ushort4*)&As[s >> 4][(s & 15) * 4] = u;
    }
#pragma unroll
    for (int i = 0; i < 4; ++i) {
      int s = tid + i * 256;
      *(uint4*)&Bs[s >> 3][(s & 7) * 8] = breg[i];
    }
    // ---- issue next tile's loads (overlap with MFMA below) ----
    if (ks < 7) {
#pragma unroll
      for (int i = 0; i < 8; ++i) {
        int s = tid + i * 256;
        areg[i] = *(const float4*)(x1b + (size_t)(s >> 4) * 512 + (ks + 1) * 64 + (s & 15) * 4);
      }
#pragma unroll
      for (int i = 0; i < 4; ++i) {
        int s = tid + i * 256;
        breg[i] = *(const uint4*)(wb + (size_t)(s >> 3) * 512 + (ks + 1) * 64 + (s & 7) * 8);
      }
    }
    __syncthreads();                // tile ks ready
    // ---- MFMA: K=64 in two 32-chunks ----
#pragma unroll
    for (int kk = 0; kk < 2; ++kk) {
      bf16x8 af[4], bfr[4];
#pragma unroll
      for (int mf = 0; mf < 4; ++mf)
        af[mf] = *(bf16x8*)&As[wr * 64 + mf * 16 + lr][kk * 32 + lg * 8];
#pragma unroll
      for (int nf = 0; nf < 4; ++nf)
        bfr[nf] = *(bf16x8*)&Bs[wc * 64 + nf * 16 + lr][kk * 32 + lg * 8];
#pragma unroll
      for (int mf = 0; mf < 4; ++mf)
#pragma unroll
        for (int nf = 0; nf < 4; ++nf)
          acc[mf][nf] = __builtin_amdgcn_mfma_f32_16x16x32_bf16(
              af[mf], bfr[nf], acc[mf][nf], 0, 0, 0);
    }
  }

  // ---- sum(x1[b]) partial reduction (nt==0 blocks only) ----
  if (nt == 0) {
    float v = ssum;
#pragma unroll
    for (int off = 32; off > 0; off >>= 1) v += __shfl_down(v, off, 64);
    if (lane == 0) sred[wid] = v;
  }
  __syncthreads();
  if (nt == 0 && tid == 0)
    atomicAdd(&S[b], sred[0] + sred[1] + sred[2] + sred[3]);

  // ---- epilogue: tanh(s2 + s1)*Va[t], reduce over t within tile ----
  // C/D layout: col = lane&15, row = (lane>>4)*4 + reg
  const float* s1b = s1 + b * 512;
#pragma unroll
  for (int nf = 0; nf < 4; ++nf) {
    const int dcol = nt * 128 + wc * 64 + nf * 16 + lr;
    const float s1c = s1b[dcol];
    float p = 0.f;
#pragma unroll
    for (int mf = 0; mf < 4; ++mf) {
      const int rbase = mt * 128 + wr * 64 + mf * 16 + lg * 4;
#pragma unroll
      for (int rr = 0; rr < 4; ++rr) {
        float v = acc[mf][nf][rr] + s1c;
        float e = __expf(2.f * v);
        float th = 1.f - 2.f / (e + 1.f);   // tanh(v), NaN-safe
        p = fmaf(th, Va[rbase + rr], p);
      }
    }
    p += __shfl_xor(p, 16, 64);
    p += __shfl_xor(p, 32, 64);
    if (lg == 0) atomicAdd(&o[b * 512 + dcol], p);
  }
}

// softmax over D per b, scale by S[b]
__global__ __launch_bounds__(512) void finalize(const float* __restrict__ o,
                                                const float* __restrict__ S,
                                                float* __restrict__ out) {
  __shared__ float redm[8];
  __shared__ float reds[8];
  const int b = blockIdx.x;
  const int d = threadIdx.x;
  const int wid = d >> 6, lane = d & 63;
  const float v = o[b * 512 + d];
  float m = v;
#pragma unroll
  for (int off = 32; off > 0; off >>= 1) m = fmaxf(m, __shfl_xor(m, off, 64));
  if (lane == 0) redm[wid] = m;
  __syncthreads();
  float bm = redm[0];
#pragma unroll
  for (int i = 1; i < 8; ++i) bm = fmaxf(bm, redm[i]);
  const float e = __expf(v - bm);
  float s = e;
#pragma unroll
  for (int off = 32; off > 0; off >>= 1) s += __shfl_xor(s, off, 64);
  if (lane == 0) reds[wid] = s;
  __syncthreads();
  float bs = 0.f;
#pragma unroll
  for (int i = 0; i < 8; ++i) bs += reds[i];
  out[b * 512 + d] = (e / bs) * S[b];
}

extern "C" void kernel_launch(void* const* d_in, const int* in_sizes, int n_in,
                              void* d_out, int out_size, void* d_ws, size_t ws_size,
                              hipStream_t stream) {
  const float* x0 = (const float*)d_in[0];
  const float* x1 = (const float*)d_in[1];
  const float* Wa = (const float*)d_in[2];
  const float* Wh = (const float*)d_in[3];
  const float* Va = (const float*)d_in[4];
  float* out = (float*)d_out;

  char* ws = (char*)d_ws;
  ushort* WhT = (ushort*)(ws);             // 512*512*2   = 524288 B
  float*  s1  = (float*)(ws + 524288);     // 32*512*4    = 65536 B
  float*  o   = (float*)(ws + 589824);     // 32*512*4    = 65536 B
  float*  S   = (float*)(ws + 655360);     // 32*4        = 128 B

  hipMemsetAsync(o, 0, 65536 + 128, stream);       // zero o and S (contiguous)
  prep_wht<<<64, 256, 0, stream>>>(Wh, WhT);
  prep_s1<<<64, 256, 0, stream>>>(x0, Wa, s1);
  main_gemm<<<2048, 256, 0, stream>>>(x1, WhT, s1, Va, o, S);
  finalize<<<32, 512, 0, stream>>>(o, S, out);
}

// Round 5
// 299.051 us; speedup vs baseline: 1.3977x; 1.3977x over previous
//
#include <hip/hip_runtime.h>
#include <hip/hip_bf16.h>

// B=32, T=2048, D=512
// out[b,d] = softmax_d( sum_t Va[t]*tanh((x0@Wa)[b,d] + (x1@Wh)[b,t,d]) ) * sum_{t,i} x1[b,t,i]

typedef __attribute__((ext_vector_type(8))) short bf16x8;
typedef __attribute__((ext_vector_type(4))) float f32x4;

__device__ __forceinline__ ushort f2bf(float f) {
  __hip_bfloat16 h = __float2bfloat16(f);
  union { __hip_bfloat16 h; ushort u; } c; c.h = h;
  return c.u;
}

__device__ __forceinline__ unsigned cvt2u(float x, float y) {
  float2 f; f.x = x; f.y = y;
  __hip_bfloat162 h = __float22bfloat162_rn(f);    // v_cvt_pk_bf16_f32
  union { __hip_bfloat162 h; unsigned u; } c; c.h = h;
  return c.u;
}

__device__ __forceinline__ ushort2 cvt2(float x, float y) {
  union { unsigned u; ushort2 s; } c; c.u = cvt2u(x, y);
  return c.s;
}

// async global -> LDS, 16B per lane. LDS dest must be wave-uniform base (+lane*16 by HW).
__device__ __forceinline__ void gload16(const void* g, void* l) {
  __builtin_amdgcn_global_load_lds(
      (const __attribute__((address_space(1))) unsigned*)g,
      (__attribute__((address_space(3))) unsigned*)l, 16, 0, 0);
}

// ---------------- fused prep: x1->bf16 + per-b sum | WhT transpose | s1 ----------------
__global__ __launch_bounds__(256) void prep(
    const float* __restrict__ x1, const float* __restrict__ Wh,
    const float* __restrict__ x0, const float* __restrict__ Wa,
    ushort* __restrict__ x1bf, ushort* __restrict__ WhT,
    float* __restrict__ s1, float* __restrict__ S) {
  __shared__ float tile[64][65];
  __shared__ float sred[4];
  const int bid = blockIdx.x, tid = threadIdx.x;

  if (bid < 2048) {
    // ---- x1 f32 -> bf16 (RNE) + partial sum over the block's 16384 elems ----
    const int b = bid >> 6, seg = bid & 63;
    const size_t base = (size_t)b * 1048576 + (size_t)seg * 16384;   // f32 elems
    const float4* src = (const float4*)(x1 + base);
    float ssum = 0.f;
#pragma unroll
    for (int i = 0; i < 8; ++i) {
      int f8 = tid + i * 256;
      float4 a = src[f8 * 2];
      float4 c = src[f8 * 2 + 1];
      ssum += (a.x + a.y) + (a.z + a.w) + (c.x + c.y) + (c.z + c.w);
      uint4 w;
      w.x = cvt2u(a.x, a.y); w.y = cvt2u(a.z, a.w);
      w.z = cvt2u(c.x, c.y); w.w = cvt2u(c.z, c.w);
      *(uint4*)(x1bf + base + (size_t)f8 * 8) = w;
    }
    const int wid = tid >> 6, lane = tid & 63;
    float v = ssum;
#pragma unroll
    for (int off = 32; off > 0; off >>= 1) v += __shfl_down(v, off, 64);
    if (lane == 0) sred[wid] = v;
    __syncthreads();
    if (tid == 0) atomicAdd(&S[b], sred[0] + sred[1] + sred[2] + sred[3]);
  } else if (bid < 2112) {
    // ---- Wh (K x N row-major f32) -> WhT bf16 (N x K), tiled transpose ----
    const int t = bid - 2048;
    const int bx = t & 7;     // n-tile
    const int by = t >> 3;    // k-tile
    const int c  = tid & 63;
    const int r0 = tid >> 6;
#pragma unroll
    for (int i = 0; i < 16; ++i) {
      int r = r0 * 16 + i;
      tile[r][c] = Wh[(size_t)(by * 64 + r) * 512 + bx * 64 + c];
    }
    __syncthreads();
#pragma unroll
    for (int i = 0; i < 16; ++i) {
      int r = r0 * 16 + i;
      WhT[(size_t)(bx * 64 + r) * 512 + by * 64 + c] = f2bf(tile[c][r]);
    }
  } else {
    // ---- s1[b,d] = sum_k x0[b,k]*Wa[k,d] ----
    const int t = bid - 2112;
    const int b = t >> 1;
    const int d = (t & 1) * 256 + tid;
    const float* x0b = x0 + b * 512;
    float acc = 0.f;
#pragma unroll 8
    for (int k = 0; k < 512; ++k) acc = fmaf(x0b[k], Wa[(size_t)k * 512 + d], acc);
    s1[b * 512 + d] = acc;
  }
}

// ---------------- main GEMM (bf16 A and B, global_load_lds + XOR swizzle) ----------------
__global__ __launch_bounds__(256) void main_bf(
    const ushort* __restrict__ x1bf, const ushort* __restrict__ WhT,
    const float* __restrict__ s1, const float* __restrict__ Va,
    float* __restrict__ o) {
  __shared__ __align__(16) ushort As[8192];   // 128 rows x 128 B, XOR-swizzled content
  __shared__ __align__(16) ushort Bs[8192];

  // XCD-chunked swizzle (bijective: 2048 = 8*256)
  const int phys = blockIdx.x;
  const int lid  = (phys & 7) * 256 + (phys >> 3);
  const int b    = lid >> 6;
  const int mt   = (lid >> 2) & 15;
  const int nt   = lid & 3;

  const int tid  = threadIdx.x;
  const int wid  = tid >> 6, lane = tid & 63;
  const int wr   = wid >> 1, wc = wid & 1;     // 2x2 wave grid, 64x64 each
  const int lr   = lane & 15, lg = lane >> 4;

  f32x4 acc[4][4];
  const f32x4 zero = {0.f, 0.f, 0.f, 0.f};
#pragma unroll
  for (int mf = 0; mf < 4; ++mf)
#pragma unroll
    for (int nf = 0; nf < 4; ++nf) acc[mf][nf] = zero;

  const char* gA = (const char*)(x1bf + (size_t)(b * 2048 + mt * 128) * 512);
  const char* gB = (const char*)(WhT + (size_t)(nt * 128) * 512);
  // staging: thread covers LDS bytes [i*4096 + tid*16); row = i*32 + (tid>>3), col = (tid&7)*16
  // source col is XOR-swizzled so that (linear LDS dest) == swizzled storage
  const int rstage = tid >> 3;
  const int cswz   = (((tid & 7) ^ ((tid >> 3) & 7)) << 4);
  char* lA = (char*)As + wid * 1024;
  char* lB = (char*)Bs + wid * 1024;

  for (int ks = 0; ks < 8; ++ks) {
    __syncthreads();               // previous tile consumed
#pragma unroll
    for (int i = 0; i < 4; ++i) {
      const size_t roff = (size_t)(i * 32 + rstage) * 1024 + (size_t)ks * 128 + cswz;
      gload16(gA + roff, lA + i * 4096);
      gload16(gB + roff, lB + i * 4096);
    }
    __syncthreads();               // vmcnt drained -> tile ks ready
    const int rsw = (lr & 7) << 4;
#pragma unroll
    for (int kk = 0; kk < 2; ++kk) {
      bf16x8 af[4], bfr[4];
#pragma unroll
      for (int mf = 0; mf < 4; ++mf)
        af[mf] = *(const bf16x8*)((const char*)As +
                   (wr * 64 + mf * 16 + lr) * 128 + ((kk * 64 + lg * 16) ^ rsw));
#pragma unroll
      for (int nf = 0; nf < 4; ++nf)
        bfr[nf] = *(const bf16x8*)((const char*)Bs +
                   (wc * 64 + nf * 16 + lr) * 128 + ((kk * 64 + lg * 16) ^ rsw));
#pragma unroll
      for (int mf = 0; mf < 4; ++mf)
#pragma unroll
        for (int nf = 0; nf < 4; ++nf)
          acc[mf][nf] = __builtin_amdgcn_mfma_f32_16x16x32_bf16(
              af[mf], bfr[nf], acc[mf][nf], 0, 0, 0);
    }
  }

  // ---- epilogue: tanh(s2+s1)*Va[t], reduce over t, atomicAdd ----
  // C/D layout: col = lane&15, row = (lane>>4)*4 + reg
  const float* s1b = s1 + b * 512;
#pragma unroll
  for (int nf = 0; nf < 4; ++nf) {
    const int dcol = nt * 128 + wc * 64 + nf * 16 + lr;
    const float s1c = s1b[dcol];
    float p = 0.f;
#pragma unroll
    for (int mf = 0; mf < 4; ++mf) {
      const int rbase = mt * 128 + wr * 64 + mf * 16 + lg * 4;
#pragma unroll
      for (int rr = 0; rr < 4; ++rr) {
        float v = acc[mf][nf][rr] + s1c;
        float e = __expf(2.f * v);
        float th = 1.f - 2.f / (e + 1.f);   // tanh, NaN-safe
        p = fmaf(th, Va[rbase + rr], p);
      }
    }
    p += __shfl_xor(p, 16, 64);
    p += __shfl_xor(p, 32, 64);
    if (lg == 0) atomicAdd(&o[b * 512 + dcol], p);
  }
}

// ---------------- fallback main (round-1, f32 A staged with in-kernel cvt) ----------------
__global__ __launch_bounds__(256) void main_f32(
    const float* __restrict__ x1, const ushort* __restrict__ WhT,
    const float* __restrict__ s1, const float* __restrict__ Va,
    float* __restrict__ o, float* __restrict__ S) {
  __shared__ ushort As[128][72];
  __shared__ ushort Bs[128][72];
  __shared__ float sred[4];

  const int phys = blockIdx.x;
  const int lid  = (phys & 7) * 256 + (phys >> 3);
  const int b    = lid >> 6;
  const int mt   = (lid >> 2) & 15;
  const int nt   = lid & 3;

  const int tid  = threadIdx.x;
  const int wid  = tid >> 6, lane = tid & 63;
  const int wr   = wid >> 1, wc = wid & 1;
  const int lr   = lane & 15, lg = lane >> 4;

  f32x4 acc[4][4];
  const f32x4 zero = {0.f, 0.f, 0.f, 0.f};
#pragma unroll
  for (int mf = 0; mf < 4; ++mf)
#pragma unroll
    for (int nf = 0; nf < 4; ++nf) acc[mf][nf] = zero;

  float ssum = 0.f;
  const float*  x1b = x1 + (size_t)(b * 2048 + mt * 128) * 512;
  const ushort* wb  = WhT + (size_t)(nt * 128) * 512;

  for (int ks = 0; ks < 8; ++ks) {
    __syncthreads();
#pragma unroll
    for (int i = 0; i < 8; ++i) {
      int s = tid + i * 256;
      int row = s >> 4, c4 = s & 15;
      const float4 a = *(const float4*)(x1b + (size_t)row * 512 + ks * 64 + c4 * 4);
      if (nt == 0) ssum += (a.x + a.y) + (a.z + a.w);
      ushort2 lo = cvt2(a.x, a.y), hi = cvt2(a.z, a.w);
      ushort4 u; u.x = lo.x; u.y = lo.y; u.z = hi.x; u.w = hi.y;
      *(ushort4*)&As[row][c4 * 4] = u;
    }
#pragma unroll
    for (int i = 0; i < 4; ++i) {
      int s = tid + i * 256;
      *(uint4*)&Bs[s >> 3][(s & 7) * 8] =
          *(const uint4*)(wb + (size_t)(s >> 3) * 512 + ks * 64 + (s & 7) * 8);
    }
    __syncthreads();
#pragma unroll
    for (int kk = 0; kk < 2; ++kk) {
      bf16x8 af[4], bfr[4];
#pragma unroll
      for (int mf = 0; mf < 4; ++mf)
        af[mf] = *(bf16x8*)&As[wr * 64 + mf * 16 + lr][kk * 32 + lg * 8];
#pragma unroll
      for (int nf = 0; nf < 4; ++nf)
        bfr[nf] = *(bf16x8*)&Bs[wc * 64 + nf * 16 + lr][kk * 32 + lg * 8];
#pragma unroll
      for (int mf = 0; mf < 4; ++mf)
#pragma unroll
        for (int nf = 0; nf < 4; ++nf)
          acc[mf][nf] = __builtin_amdgcn_mfma_f32_16x16x32_bf16(
              af[mf], bfr[nf], acc[mf][nf], 0, 0, 0);
    }
  }

  if (nt == 0) {
    float v = ssum;
#pragma unroll
    for (int off = 32; off > 0; off >>= 1) v += __shfl_down(v, off, 64);
    if (lane == 0) sred[wid] = v;
  }
  __syncthreads();
  if (nt == 0 && tid == 0)
    atomicAdd(&S[b], sred[0] + sred[1] + sred[2] + sred[3]);

  const float* s1b = s1 + b * 512;
#pragma unroll
  for (int nf = 0; nf < 4; ++nf) {
    const int dcol = nt * 128 + wc * 64 + nf * 16 + lr;
    const float s1c = s1b[dcol];
    float p = 0.f;
#pragma unroll
    for (int mf = 0; mf < 4; ++mf) {
      const int rbase = mt * 128 + wr * 64 + mf * 16 + lg * 4;
#pragma unroll
      for (int rr = 0; rr < 4; ++rr) {
        float v = acc[mf][nf][rr] + s1c;
        float e = __expf(2.f * v);
        float th = 1.f - 2.f / (e + 1.f);
        p = fmaf(th, Va[rbase + rr], p);
      }
    }
    p += __shfl_xor(p, 16, 64);
    p += __shfl_xor(p, 32, 64);
    if (lg == 0) atomicAdd(&o[b * 512 + dcol], p);
  }
}

// small fallback preps
__global__ __launch_bounds__(256) void prep_wht(const float* __restrict__ Wh,
                                                ushort* __restrict__ WhT) {
  __shared__ float tile[64][65];
  const int bx = blockIdx.x & 7, by = blockIdx.x >> 3;
  const int c = threadIdx.x & 63, r0 = threadIdx.x >> 6;
#pragma unroll
  for (int i = 0; i < 16; ++i) {
    int r = r0 * 16 + i;
    tile[r][c] = Wh[(size_t)(by * 64 + r) * 512 + bx * 64 + c];
  }
  __syncthreads();
#pragma unroll
  for (int i = 0; i < 16; ++i) {
    int r = r0 * 16 + i;
    WhT[(size_t)(bx * 64 + r) * 512 + by * 64 + c] = f2bf(tile[c][r]);
  }
}

__global__ __launch_bounds__(256) void prep_s1(const float* __restrict__ x0,
                                               const float* __restrict__ Wa,
                                               float* __restrict__ s1) {
  const int b = blockIdx.x >> 1;
  const int d = (blockIdx.x & 1) * 256 + threadIdx.x;
  const float* x0b = x0 + b * 512;
  float acc = 0.f;
#pragma unroll 8
  for (int k = 0; k < 512; ++k) acc = fmaf(x0b[k], Wa[(size_t)k * 512 + d], acc);
  s1[b * 512 + d] = acc;
}

// softmax over D per b, scale by S[b]
__global__ __launch_bounds__(512) void finalize(const float* __restrict__ o,
                                                const float* __restrict__ S,
                                                float* __restrict__ out) {
  __shared__ float redm[8];
  __shared__ float reds[8];
  const int b = blockIdx.x;
  const int d = threadIdx.x;
  const int wid = d >> 6, lane = d & 63;
  const float v = o[b * 512 + d];
  float m = v;
#pragma unroll
  for (int off = 32; off > 0; off >>= 1) m = fmaxf(m, __shfl_xor(m, off, 64));
  if (lane == 0) redm[wid] = m;
  __syncthreads();
  float bm = redm[0];
#pragma unroll
  for (int i = 1; i < 8; ++i) bm = fmaxf(bm, redm[i]);
  const float e = __expf(v - bm);
  float s = e;
#pragma unroll
  for (int off = 32; off > 0; off >>= 1) s += __shfl_xor(s, off, 64);
  if (lane == 0) reds[wid] = s;
  __syncthreads();
  float bs = 0.f;
#pragma unroll
  for (int i = 0; i < 8; ++i) bs += reds[i];
  out[b * 512 + d] = (e / bs) * S[b];
}

extern "C" void kernel_launch(void* const* d_in, const int* in_sizes, int n_in,
                              void* d_out, int out_size, void* d_ws, size_t ws_size,
                              hipStream_t stream) {
  const float* x0 = (const float*)d_in[0];
  const float* x1 = (const float*)d_in[1];
  const float* Wa = (const float*)d_in[2];
  const float* Wh = (const float*)d_in[3];
  const float* Va = (const float*)d_in[4];
  float* out = (float*)d_out;

  char* ws = (char*)d_ws;
  ushort* WhT  = (ushort*)(ws);              // 524288 B
  float*  s1   = (float*)(ws + 524288);      // 65536 B
  float*  o    = (float*)(ws + 589824);      // 65536 B
  float*  S    = (float*)(ws + 655360);      // 512 B (padded)
  ushort* x1bf = (ushort*)(ws + 655872);     // 67108864 B

  hipMemsetAsync(o, 0, 65536 + 512, stream);          // zero o and S

  if (ws_size >= 67764736ull) {
    prep<<<2176, 256, 0, stream>>>(x1, Wh, x0, Wa, x1bf, WhT, s1, S);
    main_bf<<<2048, 256, 0, stream>>>(x1bf, WhT, s1, Va, o);
  } else {
    prep_wht<<<64, 256, 0, stream>>>(Wh, WhT);
    prep_s1<<<64, 256, 0, stream>>>(x0, Wa, s1);
    main_f32<<<2048, 256, 0, stream>>>(x1, WhT, s1, Va, o, S);
  }
  finalize<<<32, 512, 0, stream>>>(o, S, out);
}

// Round 7
// 298.435 us; speedup vs baseline: 1.4006x; 1.0021x over previous
//
#include <hip/hip_runtime.h>
#include <hip/hip_bf16.h>

// B=32, T=2048, D=512
// out[b,d] = softmax_d( sum_t Va[t]*tanh((x0@Wa)[b,d] + (x1@Wh)[b,t,d]) ) * sum_{t,i} x1[b,t,i]

typedef __attribute__((ext_vector_type(8))) short bf16x8;
typedef __attribute__((ext_vector_type(4))) float f32x4;

__device__ __forceinline__ ushort f2bf(float f) {
  __hip_bfloat16 h = __float2bfloat16(f);
  union { __hip_bfloat16 h; ushort u; } c; c.h = h;
  return c.u;
}

__device__ __forceinline__ unsigned cvt2u(float x, float y) {
  float2 f; f.x = x; f.y = y;
  __hip_bfloat162 h = __float22bfloat162_rn(f);    // v_cvt_pk_bf16_f32
  union { __hip_bfloat162 h; unsigned u; } c; c.h = h;
  return c.u;
}

__device__ __forceinline__ ushort2 cvt2(float x, float y) {
  union { unsigned u; ushort2 s; } c; c.u = cvt2u(x, y);
  return c.s;
}

// async global -> LDS, 16B per lane. LDS dest must be wave-uniform base (+lane*16 by HW).
__device__ __forceinline__ void gload16(const void* g, void* l) {
  __builtin_amdgcn_global_load_lds(
      (const __attribute__((address_space(1))) unsigned*)g,
      (__attribute__((address_space(3))) unsigned*)l, 16, 0, 0);
}

// ---------------- fused prep: x1->bf16 + per-b sum | WhT transpose | s1 ----------------
__global__ __launch_bounds__(256) void prep(
    const float* __restrict__ x1, const float* __restrict__ Wh,
    const float* __restrict__ x0, const float* __restrict__ Wa,
    ushort* __restrict__ x1bf, ushort* __restrict__ WhT,
    float* __restrict__ s1, float* __restrict__ S) {
  __shared__ float tile[64][65];
  __shared__ float sred[4];
  const int bid = blockIdx.x, tid = threadIdx.x;

  if (bid < 2048) {
    // ---- x1 f32 -> bf16 (RNE) + partial sum; 16384 elems = 4096 float4 per block ----
    // Batched loads (8 in flight, lane-contiguous) to get MLP; round-5 fix for the
    // 32-VGPR serialization that left prep latency-bound at 1.5 TB/s.
    const int b = bid >> 6, seg = bid & 63;
    const size_t base = (size_t)b * 1048576 + (size_t)seg * 16384;   // f32 elems
    const float4* src = (const float4*)(x1 + base);
    ushort* dst = x1bf + base;
    float ssum = 0.f;
#pragma unroll
    for (int half = 0; half < 2; ++half) {
      float4 v[8];
#pragma unroll
      for (int j = 0; j < 8; ++j)
        v[j] = src[half * 2048 + j * 256 + tid];
#pragma unroll
      for (int j = 0; j < 8; ++j) {
        float4 a = v[j];
        ssum += (a.x + a.y) + (a.z + a.w);
        uint2 w;
        w.x = cvt2u(a.x, a.y);
        w.y = cvt2u(a.z, a.w);
        *(uint2*)(dst + (size_t)(half * 2048 + j * 256 + tid) * 4) = w;
      }
    }
    const int wid = tid >> 6, lane = tid & 63;
    float v = ssum;
#pragma unroll
    for (int off = 32; off > 0; off >>= 1) v += __shfl_down(v, off, 64);
    if (lane == 0) sred[wid] = v;
    __syncthreads();
    if (tid == 0) atomicAdd(&S[b], sred[0] + sred[1] + sred[2] + sred[3]);
  } else if (bid < 2112) {
    // ---- Wh (K x N row-major f32) -> WhT bf16 (N x K), tiled transpose ----
    const int t = bid - 2048;
    const int bx = t & 7;     // n-tile
    const int by = t >> 3;    // k-tile
    const int c  = tid & 63;
    const int r0 = tid >> 6;
#pragma unroll
    for (int i = 0; i < 16; ++i) {
      int r = r0 * 16 + i;
      tile[r][c] = Wh[(size_t)(by * 64 + r) * 512 + bx * 64 + c];
    }
    __syncthreads();
#pragma unroll
    for (int i = 0; i < 16; ++i) {
      int r = r0 * 16 + i;
      WhT[(size_t)(bx * 64 + r) * 512 + by * 64 + c] = f2bf(tile[c][r]);
    }
  } else {
    // ---- s1[b,d] = sum_k x0[b,k]*Wa[k,d] ----
    const int t = bid - 2112;
    const int b = t >> 1;
    const int d = (t & 1) * 256 + tid;
    const float* x0b = x0 + b * 512;
    float acc = 0.f;
#pragma unroll 8
    for (int k = 0; k < 512; ++k) acc = fmaf(x0b[k], Wa[(size_t)k * 512 + d], acc);
    s1[b * 512 + d] = acc;
  }
}

// ---------------- main GEMM (bf16 A and B, global_load_lds + XOR swizzle) ----------------
__global__ __launch_bounds__(256) void main_bf(
    const ushort* __restrict__ x1bf, const ushort* __restrict__ WhT,
    const float* __restrict__ s1, const float* __restrict__ Va,
    float* __restrict__ o) {
  __shared__ __align__(16) ushort As[8192];   // 128 rows x 128 B, XOR-swizzled content
  __shared__ __align__(16) ushort Bs[8192];

  // XCD-chunked swizzle (bijective: 2048 = 8*256)
  const int phys = blockIdx.x;
  const int lid  = (phys & 7) * 256 + (phys >> 3);
  const int b    = lid >> 6;
  const int mt   = (lid >> 2) & 15;
  const int nt   = lid & 3;

  const int tid  = threadIdx.x;
  const int wid  = tid >> 6, lane = tid & 63;
  const int wr   = wid >> 1, wc = wid & 1;     // 2x2 wave grid, 64x64 each
  const int lr   = lane & 15, lg = lane >> 4;

  f32x4 acc[4][4];
  const f32x4 zero = {0.f, 0.f, 0.f, 0.f};
#pragma unroll
  for (int mf = 0; mf < 4; ++mf)
#pragma unroll
    for (int nf = 0; nf < 4; ++nf) acc[mf][nf] = zero;

  const char* gA = (const char*)(x1bf + (size_t)(b * 2048 + mt * 128) * 512);
  const char* gB = (const char*)(WhT + (size_t)(nt * 128) * 512);
  // staging: thread covers LDS bytes [i*4096 + tid*16); row = i*32 + (tid>>3), col = (tid&7)*16
  // source col is XOR-swizzled so that (linear LDS dest) == swizzled storage
  const int rstage = tid >> 3;
  const int cswz   = (((tid & 7) ^ ((tid >> 3) & 7)) << 4);
  char* lA = (char*)As + wid * 1024;
  char* lB = (char*)Bs + wid * 1024;

  for (int ks = 0; ks < 8; ++ks) {
    __syncthreads();               // previous tile consumed
#pragma unroll
    for (int i = 0; i < 4; ++i) {
      const size_t roff = (size_t)(i * 32 + rstage) * 1024 + (size_t)ks * 128 + cswz;
      gload16(gA + roff, lA + i * 4096);
      gload16(gB + roff, lB + i * 4096);
    }
    __syncthreads();               // vmcnt drained -> tile ks ready
    const int rsw = (lr & 7) << 4;
#pragma unroll
    for (int kk = 0; kk < 2; ++kk) {
      bf16x8 af[4], bfr[4];
#pragma unroll
      for (int mf = 0; mf < 4; ++mf)
        af[mf] = *(const bf16x8*)((const char*)As +
                   (wr * 64 + mf * 16 + lr) * 128 + ((kk * 64 + lg * 16) ^ rsw));
#pragma unroll
      for (int nf = 0; nf < 4; ++nf)
        bfr[nf] = *(const bf16x8*)((const char*)Bs +
                   (wc * 64 + nf * 16 + lr) * 128 + ((kk * 64 + lg * 16) ^ rsw));
#pragma unroll
      for (int mf = 0; mf < 4; ++mf)
#pragma unroll
        for (int nf = 0; nf < 4; ++nf)
          acc[mf][nf] = __builtin_amdgcn_mfma_f32_16x16x32_bf16(
              af[mf], bfr[nf], acc[mf][nf], 0, 0, 0);
    }
  }

  // ---- epilogue: tanh(s2+s1)*Va[t], reduce over t, atomicAdd ----
  // C/D layout: col = lane&15, row = (lane>>4)*4 + reg
  const float* s1b = s1 + b * 512;
#pragma unroll
  for (int nf = 0; nf < 4; ++nf) {
    const int dcol = nt * 128 + wc * 64 + nf * 16 + lr;
    const float s1c = s1b[dcol];
    float p = 0.f;
#pragma unroll
    for (int mf = 0; mf < 4; ++mf) {
      const int rbase = mt * 128 + wr * 64 + mf * 16 + lg * 4;
#pragma unroll
      for (int rr = 0; rr < 4; ++rr) {
        float v = acc[mf][nf][rr] + s1c;
        float e = __expf(2.f * v);
        float th = 1.f - 2.f / (e + 1.f);   // tanh, NaN-safe
        p = fmaf(th, Va[rbase + rr], p);
      }
    }
    p += __shfl_xor(p, 16, 64);
    p += __shfl_xor(p, 32, 64);
    if (lg == 0) atomicAdd(&o[b * 512 + dcol], p);
  }
}

// ---------------- fallback main (round-1, f32 A staged with in-kernel cvt) ----------------
__global__ __launch_bounds__(256) void main_f32(
    const float* __restrict__ x1, const ushort* __restrict__ WhT,
    const float* __restrict__ s1, const float* __restrict__ Va,
    float* __restrict__ o, float* __restrict__ S) {
  __shared__ ushort As[128][72];
  __shared__ ushort Bs[128][72];
  __shared__ float sred[4];

  const int phys = blockIdx.x;
  const int lid  = (phys & 7) * 256 + (phys >> 3);
  const int b    = lid >> 6;
  const int mt   = (lid >> 2) & 15;
  const int nt   = lid & 3;

  const int tid  = threadIdx.x;
  const int wid  = tid >> 6, lane = tid & 63;
  const int wr   = wid >> 1, wc = wid & 1;
  const int lr   = lane & 15, lg = lane >> 4;

  f32x4 acc[4][4];
  const f32x4 zero = {0.f, 0.f, 0.f, 0.f};
#pragma unroll
  for (int mf = 0; mf < 4; ++mf)
#pragma unroll
    for (int nf = 0; nf < 4; ++nf) acc[mf][nf] = zero;

  float ssum = 0.f;
  const float*  x1b = x1 + (size_t)(b * 2048 + mt * 128) * 512;
  const ushort* wb  = WhT + (size_t)(nt * 128) * 512;

  for (int ks = 0; ks < 8; ++ks) {
    __syncthreads();
#pragma unroll
    for (int i = 0; i < 8; ++i) {
      int s = tid + i * 256;
      int row = s >> 4, c4 = s & 15;
      const float4 a = *(const float4*)(x1b + (size_t)row * 512 + ks * 64 + c4 * 4);
      if (nt == 0) ssum += (a.x + a.y) + (a.z + a.w);
      ushort2 lo = cvt2(a.x, a.y), hi = cvt2(a.z, a.w);
      ushort4 u; u.x = lo.x; u.y = lo.y; u.z = hi.x; u.w = hi.y;
      *(ushort4*)&As[row][c4 * 4] = u;
    }
#pragma unroll
    for (int i = 0; i < 4; ++i) {
      int s = tid + i * 256;
      *(uint4*)&Bs[s >> 3][(s & 7) * 8] =
          *(const uint4*)(wb + (size_t)(s >> 3) * 512 + ks * 64 + (s & 7) * 8);
    }
    __syncthreads();
#pragma unroll
    for (int kk = 0; kk < 2; ++kk) {
      bf16x8 af[4], bfr[4];
#pragma unroll
      for (int mf = 0; mf < 4; ++mf)
        af[mf] = *(bf16x8*)&As[wr * 64 + mf * 16 + lr][kk * 32 + lg * 8];
#pragma unroll
      for (int nf = 0; nf < 4; ++nf)
        bfr[nf] = *(bf16x8*)&Bs[wc * 64 + nf * 16 + lr][kk * 32 + lg * 8];
#pragma unroll
      for (int mf = 0; mf < 4; ++mf)
#pragma unroll
        for (int nf = 0; nf < 4; ++nf)
          acc[mf][nf] = __builtin_amdgcn_mfma_f32_16x16x32_bf16(
              af[mf], bfr[nf], acc[mf][nf], 0, 0, 0);
    }
  }

  if (nt == 0) {
    float v = ssum;
#pragma unroll
    for (int off = 32; off > 0; off >>= 1) v += __shfl_down(v, off, 64);
    if (lane == 0) sred[wid] = v;
  }
  __syncthreads();
  if (nt == 0 && tid == 0)
    atomicAdd(&S[b], sred[0] + sred[1] + sred[2] + sred[3]);

  const float* s1b = s1 + b * 512;
#pragma unroll
  for (int nf = 0; nf < 4; ++nf) {
    const int dcol = nt * 128 + wc * 64 + nf * 16 + lr;
    const float s1c = s1b[dcol];
    float p = 0.f;
#pragma unroll
    for (int mf = 0; mf < 4; ++mf) {
      const int rbase = mt * 128 + wr * 64 + mf * 16 + lg * 4;
#pragma unroll
      for (int rr = 0; rr < 4; ++rr) {
        float v = acc[mf][nf][rr] + s1c;
        float e = __expf(2.f * v);
        float th = 1.f - 2.f / (e + 1.f);
        p = fmaf(th, Va[rbase + rr], p);
      }
    }
    p += __shfl_xor(p, 16, 64);
    p += __shfl_xor(p, 32, 64);
    if (lg == 0) atomicAdd(&o[b * 512 + dcol], p);
  }
}

// small fallback preps
__global__ __launch_bounds__(256) void prep_wht(const float* __restrict__ Wh,
                                                ushort* __restrict__ WhT) {
  __shared__ float tile[64][65];
  const int bx = blockIdx.x & 7, by = blockIdx.x >> 3;
  const int c = threadIdx.x & 63, r0 = threadIdx.x >> 6;
#pragma unroll
  for (int i = 0; i < 16; ++i) {
    int r = r0 * 16 + i;
    tile[r][c] = Wh[(size_t)(by * 64 + r) * 512 + bx * 64 + c];
  }
  __syncthreads();
#pragma unroll
  for (int i = 0; i < 16; ++i) {
    int r = r0 * 16 + i;
    WhT[(size_t)(bx * 64 + r) * 512 + by * 64 + c] = f2bf(tile[c][r]);
  }
}

__global__ __launch_bounds__(256) void prep_s1(const float* __restrict__ x0,
                                               const float* __restrict__ Wa,
                                               float* __restrict__ s1) {
  const int b = blockIdx.x >> 1;
  const int d = (blockIdx.x & 1) * 256 + threadIdx.x;
  const float* x0b = x0 + b * 512;
  float acc = 0.f;
#pragma unroll 8
  for (int k = 0; k < 512; ++k) acc = fmaf(x0b[k], Wa[(size_t)k * 512 + d], acc);
  s1[b * 512 + d] = acc;
}

// softmax over D per b, scale by S[b]
__global__ __launch_bounds__(512) void finalize(const float* __restrict__ o,
                                                const float* __restrict__ S,
                                                float* __restrict__ out) {
  __shared__ float redm[8];
  __shared__ float reds[8];
  const int b = blockIdx.x;
  const int d = threadIdx.x;
  const int wid = d >> 6, lane = d & 63;
  const float v = o[b * 512 + d];
  float m = v;
#pragma unroll
  for (int off = 32; off > 0; off >>= 1) m = fmaxf(m, __shfl_xor(m, off, 64));
  if (lane == 0) redm[wid] = m;
  __syncthreads();
  float bm = redm[0];
#pragma unroll
  for (int i = 1; i < 8; ++i) bm = fmaxf(bm, redm[i]);
  const float e = __expf(v - bm);
  float s = e;
#pragma unroll
  for (int off = 32; off > 0; off >>= 1) s += __shfl_xor(s, off, 64);
  if (lane == 0) reds[wid] = s;
  __syncthreads();
  float bs = 0.f;
#pragma unroll
  for (int i = 0; i < 8; ++i) bs += reds[i];
  out[b * 512 + d] = (e / bs) * S[b];
}

extern "C" void kernel_launch(void* const* d_in, const int* in_sizes, int n_in,
                              void* d_out, int out_size, void* d_ws, size_t ws_size,
                              hipStream_t stream) {
  const float* x0 = (const float*)d_in[0];
  const float* x1 = (const float*)d_in[1];
  const float* Wa = (const float*)d_in[2];
  const float* Wh = (const float*)d_in[3];
  const float* Va = (const float*)d_in[4];
  float* out = (float*)d_out;

  char* ws = (char*)d_ws;
  ushort* WhT  = (ushort*)(ws);              // 524288 B
  float*  s1   = (float*)(ws + 524288);      // 65536 B
  float*  o    = (float*)(ws + 589824);      // 65536 B
  float*  S    = (float*)(ws + 655360);      // 512 B (padded)
  ushort* x1bf = (ushort*)(ws + 655872);     // 67108864 B

  hipMemsetAsync(o, 0, 65536 + 512, stream);          // zero o and S

  if (ws_size >= 67764736ull) {
    prep<<<2176, 256, 0, stream>>>(x1, Wh, x0, Wa, x1bf, WhT, s1, S);
    main_bf<<<2048, 256, 0, stream>>>(x1bf, WhT, s1, Va, o);
  } else {
    prep_wht<<<64, 256, 0, stream>>>(Wh, WhT);
    prep_s1<<<64, 256, 0, stream>>>(x0, Wa, s1);
    main_f32<<<2048, 256, 0, stream>>>(x1, WhT, s1, Va, o, S);
  }
  finalize<<<32, 512, 0, stream>>>(o, S, out);
}